// Round 7
// baseline (111.606 us; speedup 1.0000x reference)
//
#include <hip/hip_runtime.h>
#include <hip/hip_cooperative_groups.h>
#include <math.h>

namespace cg = cooperative_groups;

#define S_DIM 512
#define N_NODE 1024
#define H_DIM 128
#define Z_DIM 64
#define T_START 64
#define T_CNT 353          // end - start = 417 - 64
#define NEG_DIST 85        // S // 6
#define TIMESPAN 4
#define M_SAMP 8
#define EPS_F 1e-8f
#define DIST_B 4
#define H_CHUNKS 8         // 8 chunks of 128 nodes per h-row (64 KB each)

typedef float f4 __attribute__((ext_vector_type(4)));

// ---------------------------------------------------------------------------
// Kernel 1: pure streaming pool. ZERO atomics/fences (R4/R5 lesson: no
// cross-workgroup sync inside a BW-bound kernel on MI355X).
//   blocks [0, S_DIM):  z-row s=b (256 KB): mean -> Wz -> z_pool + znorm
//   blocks [S_DIM, S_DIM + T_CNT*8): h-chunk (64 KB): raw partial sum only.
// ---------------------------------------------------------------------------
__global__ __launch_bounds__(256) void pool_kernel(
        const float* __restrict__ all_h, const float* __restrict__ all_z,
        const float* __restrict__ Wz, const float* __restrict__ bz,
        float* __restrict__ z_pool, float* __restrict__ znorm,
        float* __restrict__ hpart) {
    __shared__ __align__(16) f4 red4[256];
    __shared__ __align__(16) float mrow[H_DIM];
    __shared__ float sred[H_DIM];
    const int tid = threadIdx.x;
    const int b = blockIdx.x;

    if (b < S_DIM) {
        // ---- z row: mean over 1024 nodes + projection + norm ----
        const int s = b;
        const int h4 = tid & 15, grp = tid >> 4;
        const f4* p = (const f4*)(all_z + (size_t)s * N_NODE * Z_DIM);
        f4 acc = {0.f, 0.f, 0.f, 0.f};
        #pragma unroll 8
        for (int n = grp; n < N_NODE; n += 16)
            acc += __builtin_nontemporal_load(&p[n * 16 + h4]);
        red4[grp * 16 + h4] = acc;
        __syncthreads();
        for (int st = 8; st >= 1; st >>= 1) {
            if (grp < st) red4[grp * 16 + h4] += red4[(grp + st) * 16 + h4];
            __syncthreads();
        }
        if (grp == 0)
            *(f4*)&mrow[h4 * 4] = red4[h4] * (1.0f / (float)N_NODE);
        __syncthreads();

        const int o = tid >> 1, half = tid & 1;
        const float* w = Wz + o * Z_DIM + half * 32;
        const float* x = mrow + half * 32;
        float ps = 0.f;
        #pragma unroll 8
        for (int k = 0; k < 32; ++k) ps = fmaf(x[k], w[k], ps);
        ps += __shfl_xor(ps, 1);
        if (half == 0) {
            float zp = ps + bz[o];
            z_pool[s * H_DIM + o] = zp;
            sred[o] = zp * zp;
        }
        __syncthreads();
        for (int st = 64; st >= 1; st >>= 1) {
            if (tid < st) sred[tid] += sred[tid + st];
            __syncthreads();
        }
        if (tid == 0) znorm[s] = sqrtf(sred[0]);
    } else {
        // ---- h chunk: raw partial sum over 128 nodes (64 KB) ----
        const int b2 = b - S_DIM;
        const int t = b2 >> 3, ch = b2 & 7;
        const int s = T_START + t;
        const int h4 = tid & 31, grp = tid >> 5;
        const int n0 = ch * (N_NODE / H_CHUNKS);
        const f4* p = (const f4*)(all_h + (size_t)s * N_NODE * H_DIM);
        f4 acc = {0.f, 0.f, 0.f, 0.f};
        #pragma unroll 8
        for (int n = n0 + grp; n < n0 + N_NODE / H_CHUNKS; n += 8)
            acc += __builtin_nontemporal_load(&p[n * 32 + h4]);
        red4[grp * 32 + h4] = acc;
        __syncthreads();
        for (int st = 4; st >= 1; st >>= 1) {
            if (grp < st) red4[grp * 32 + h4] += red4[(grp + st) * 32 + h4];
            __syncthreads();
        }
        if (grp == 0)
            *(f4*)&hpart[(size_t)b2 * H_DIM + h4 * 4] = red4[h4];
    }
}

// ---------------------------------------------------------------------------
// Kernel 2 (cooperative): nce partials + dist partials, ONE grid.sync(),
// then block 0 does the final reduction. Single legal grid-wide barrier at
// the phase boundary — not per-access fences (R4/R5 lesson).
// ---------------------------------------------------------------------------
__global__ __launch_bounds__(128) void nce_dist_final_kernel(
        const float* __restrict__ hpart,
        const float* __restrict__ Wh,   const float* __restrict__ bh,
        const float* __restrict__ Wphi, const float* __restrict__ bphi,
        const float* __restrict__ z_pool, const float* __restrict__ znorm,
        float* __restrict__ partial, float* __restrict__ dsum,
        float* __restrict__ dsq, float* __restrict__ out) {
    const int b = blockIdx.x, tid = threadIdx.x;
    __shared__ __align__(16) float mrow[H_DIM];
    __shared__ __align__(16) float hrow[H_DIM];
    __shared__ __align__(16) float cbuf[H_DIM];
    __shared__ float sred[H_DIM];
    __shared__ float sims[32];
    __shared__ float contrib[4];
    __shared__ float s_cn;

    if (b < T_CNT) {
        // combine own 8 partial sums (fixed order) -> mean row
        const float* hp = hpart + (size_t)b * (H_CHUNKS * H_DIM);
        {
            float v = 0.f;
            #pragma unroll
            for (int c = 0; c < H_CHUNKS; ++c) v += hp[c * H_DIM + tid];
            mrow[tid] = v * (1.0f / (float)N_NODE);
        }
        __syncthreads();

        const int o = tid >> 1, half = tid & 1;
        {   // hrow = mrow @ Wh^T + bh
            const f4* w4 = (const f4*)(Wh + o * H_DIM + half * 64);
            const f4* x4 = (const f4*)(mrow + half * 64);
            float ps = 0.f;
            #pragma unroll
            for (int k = 0; k < 16; ++k) {
                f4 a = w4[k], x = x4[k];
                ps = fmaf(a.x, x.x, ps); ps = fmaf(a.y, x.y, ps);
                ps = fmaf(a.z, x.z, ps); ps = fmaf(a.w, x.w, ps);
            }
            ps += __shfl_xor(ps, 1);
            if (half == 0) hrow[o] = ps + bh[o];
        }
        __syncthreads();
        {   // cbuf = hrow @ Wphi^T + bphi ; squared norm
            const f4* w4 = (const f4*)(Wphi + o * H_DIM + half * 64);
            const f4* x4 = (const f4*)(hrow + half * 64);
            float ps = 0.f;
            #pragma unroll
            for (int k = 0; k < 16; ++k) {
                f4 a = w4[k], x = x4[k];
                ps = fmaf(a.x, x.x, ps); ps = fmaf(a.y, x.y, ps);
                ps = fmaf(a.z, x.z, ps); ps = fmaf(a.w, x.w, ps);
            }
            ps += __shfl_xor(ps, 1);
            if (half == 0) {
                float cv = ps + bphi[o];
                cbuf[o] = cv;
                sred[o] = cv * cv;
            }
        }
        __syncthreads();
        for (int st = 64; st >= 1; st >>= 1) {
            if (tid < st) sred[tid] += sred[tid + st];
            __syncthreads();
        }
        if (tid == 0) s_cn = fmaxf(sqrtf(sred[0]), EPS_F);
        __syncthreads();
        const float cn = s_cn;

        // 32 (i,m) pairs, 4 lanes per cosine dot
        const int pr = tid >> 2, l4 = tid & 3;
        const int i = pr >> 3, m = pr & 7;
        const int off = (m == 0) ? 0 : (NEG_DIST + m - 1);
        const int row = T_START + b + (i + 1) + off;
        const float* zr = z_pool + row * H_DIM;
        float num = 0.f;
        #pragma unroll 8
        for (int k = l4 * 32; k < l4 * 32 + 32; ++k)
            num = fmaf(zr[k], cbuf[k], num);
        num += __shfl_xor(num, 1);
        num += __shfl_xor(num, 2);
        if (l4 == 0) sims[pr] = num / (fmaxf(znorm[row], EPS_F) * cn);
        __syncthreads();
        if (tid < 4) {
            const float* sm = sims + tid * 8;
            float mx = sm[0];
            #pragma unroll
            for (int k = 1; k < M_SAMP; ++k) mx = fmaxf(mx, sm[k]);
            float se = 0.f;
            #pragma unroll
            for (int k = 0; k < M_SAMP; ++k) se += expf(sm[k] - mx);
            contrib[tid] = sm[0] - mx - logf(se);
        }
        __syncthreads();
        if (tid == 0)
            partial[b] = contrib[0] + contrib[1] + contrib[2] + contrib[3];
    } else {
        // ---- dist chunk: column sum/sumsq of 128 z_pool rows ----
        const int ch = b - T_CNT;
        const int s0 = ch * (S_DIM / DIST_B);
        float sum = 0.f, sq = 0.f;
        for (int s = s0; s < s0 + S_DIM / DIST_B; ++s) {
            float v = z_pool[s * H_DIM + tid];
            sum += v;
            sq = fmaf(v, v, sq);
        }
        dsum[ch * H_DIM + tid] = sum;
        dsq[ch * H_DIM + tid] = sq;
    }

    // -------- single grid-wide barrier, then block 0 finishes --------
    cg::this_grid().sync();
    if (b != 0) return;

    float v = partial[tid] + ((tid + 128 < T_CNT) ? partial[tid + 128] : 0.f)
                           + ((tid + 256 < T_CNT) ? partial[tid + 256] : 0.f);
    mrow[tid] = v;
    {
        float S = 0.f, Q = 0.f;
        #pragma unroll
        for (int c = 0; c < DIST_B; ++c) {
            S += dsum[c * H_DIM + tid];
            Q += dsq[c * H_DIM + tid];
        }
        sred[tid] = Q - S * S / (float)S_DIM;
    }
    __syncthreads();
    for (int st = 64; st >= 1; st >>= 1) {
        if (tid < st) {
            mrow[tid] += mrow[tid + st];
            sred[tid] += sred[tid + st];
        }
        __syncthreads();
    }
    if (tid == 0) {
        out[0] = mrow[0] / (-1.0f * (float)T_CNT * (float)TIMESPAN);
        out[1] = sred[0] / (float)S_DIM;
    }
}

extern "C" void kernel_launch(void* const* d_in, const int* in_sizes, int n_in,
                              void* d_out, int out_size, void* d_ws, size_t ws_size,
                              hipStream_t stream) {
    const float* all_h = (const float*)d_in[0];
    const float* all_z = (const float*)d_in[1];
    const float* Wh    = (const float*)d_in[2];
    const float* bh    = (const float*)d_in[3];
    const float* Wz    = (const float*)d_in[4];
    const float* bz    = (const float*)d_in[5];
    const float* Wphi  = (const float*)d_in[6];
    const float* bphi  = (const float*)d_in[7];
    float* out = (float*)d_out;

    float* ws = (float*)d_ws;
    float* z_pool  = ws;                               // 512*128
    float* znorm   = z_pool + S_DIM * H_DIM;           // 512
    float* hpart   = znorm + S_DIM;                    // 2824*128
    float* partial = hpart + T_CNT * H_CHUNKS * H_DIM; // 353
    float* dsum    = partial + T_CNT;                  // 4*128
    float* dsq     = dsum + DIST_B * H_DIM;            // 4*128

    pool_kernel<<<S_DIM + T_CNT * H_CHUNKS, 256, 0, stream>>>(
        all_h, all_z, Wz, bz, z_pool, znorm, hpart);

    void* args[] = {(void*)&hpart, (void*)&Wh, (void*)&bh, (void*)&Wphi,
                    (void*)&bphi, (void*)&z_pool, (void*)&znorm,
                    (void*)&partial, (void*)&dsum, (void*)&dsq, (void*)&out};
    hipLaunchCooperativeKernel((void*)nce_dist_final_kernel,
                               dim3(T_CNT + DIST_B), dim3(128), args, 0, stream);
}

// Round 8
// 62.770 us; speedup vs baseline: 1.7780x; 1.7780x over previous
//
#include <hip/hip_runtime.h>
#include <math.h>

#define S_DIM 512
#define N_NODE 1024
#define H_DIM 128
#define Z_DIM 64
#define T_START 64
#define T_CNT 353          // end - start = 417 - 64
#define NEG_DIST 85        // S // 6
#define TIMESPAN 4
#define M_SAMP 8
#define EPS_F 1e-8f
#define DIST_B 4
#define H_CHUNKS 8         // 8 chunks of 128 nodes per h-row (64 KB each)

typedef float f4 __attribute__((ext_vector_type(4)));

// ---------------------------------------------------------------------------
// Kernel 1: pure streaming pool. ZERO atomics/fences (R4/R5 lesson: no
// cross-workgroup sync inside a BW-bound kernel on MI355X; R7 lesson:
// cooperative grid-sync costs ~49us under graph capture — kernel
// boundaries are the cheapest legal cross-workgroup dependency).
//   blocks [0, S_DIM):  z-row s=b (256 KB): mean -> Wz -> z_pool + znorm
//   blocks [S_DIM, S_DIM + T_CNT*8): h-chunk (64 KB): raw partial sum only.
// ---------------------------------------------------------------------------
__global__ __launch_bounds__(256) void pool_kernel(
        const float* __restrict__ all_h, const float* __restrict__ all_z,
        const float* __restrict__ Wz, const float* __restrict__ bz,
        float* __restrict__ z_pool, float* __restrict__ znorm,
        float* __restrict__ hpart) {
    __shared__ __align__(16) f4 red4[256];
    __shared__ __align__(16) float mrow[H_DIM];
    __shared__ float sred[H_DIM];
    const int tid = threadIdx.x;
    const int b = blockIdx.x;

    if (b < S_DIM) {
        // ---- z row: mean over 1024 nodes + projection + norm ----
        const int s = b;
        const int h4 = tid & 15, grp = tid >> 4;
        const f4* p = (const f4*)(all_z + (size_t)s * N_NODE * Z_DIM);
        f4 acc = {0.f, 0.f, 0.f, 0.f};
        #pragma unroll 8
        for (int n = grp; n < N_NODE; n += 16)
            acc += __builtin_nontemporal_load(&p[n * 16 + h4]);
        red4[grp * 16 + h4] = acc;
        __syncthreads();
        for (int st = 8; st >= 1; st >>= 1) {
            if (grp < st) red4[grp * 16 + h4] += red4[(grp + st) * 16 + h4];
            __syncthreads();
        }
        if (grp == 0)
            *(f4*)&mrow[h4 * 4] = red4[h4] * (1.0f / (float)N_NODE);
        __syncthreads();

        const int o = tid >> 1, half = tid & 1;
        const float* w = Wz + o * Z_DIM + half * 32;
        const float* x = mrow + half * 32;
        float ps = 0.f;
        #pragma unroll 8
        for (int k = 0; k < 32; ++k) ps = fmaf(x[k], w[k], ps);
        ps += __shfl_xor(ps, 1);
        if (half == 0) {
            float zp = ps + bz[o];
            z_pool[s * H_DIM + o] = zp;
            sred[o] = zp * zp;
        }
        __syncthreads();
        for (int st = 64; st >= 1; st >>= 1) {
            if (tid < st) sred[tid] += sred[tid + st];
            __syncthreads();
        }
        if (tid == 0) znorm[s] = sqrtf(sred[0]);
    } else {
        // ---- h chunk: raw partial sum over 128 nodes (64 KB) ----
        const int b2 = b - S_DIM;
        const int t = b2 >> 3, ch = b2 & 7;
        const int s = T_START + t;
        const int h4 = tid & 31, grp = tid >> 5;
        const int n0 = ch * (N_NODE / H_CHUNKS);
        const f4* p = (const f4*)(all_h + (size_t)s * N_NODE * H_DIM);
        f4 acc = {0.f, 0.f, 0.f, 0.f};
        #pragma unroll 8
        for (int n = n0 + grp; n < n0 + N_NODE / H_CHUNKS; n += 8)
            acc += __builtin_nontemporal_load(&p[n * 32 + h4]);
        red4[grp * 32 + h4] = acc;
        __syncthreads();
        for (int st = 4; st >= 1; st >>= 1) {
            if (grp < st) red4[grp * 32 + h4] += red4[(grp + st) * 32 + h4];
            __syncthreads();
        }
        if (grp == 0)
            *(f4*)&hpart[(size_t)b2 * H_DIM + h4 * 4] = red4[h4];
    }
}

// ---------------------------------------------------------------------------
// Kernel 2: blocks [0,T_CNT): combine 8 h-partials -> mean -> Wh -> Wphi ->
//           cnorm -> cosine sims -> log-softmax partial.
//           blocks [T_CNT, T_CNT+DIST_B): dist column sum/sumsq chunk.
// ---------------------------------------------------------------------------
__global__ __launch_bounds__(128) void nce_dist_kernel(
        const float* __restrict__ hpart,
        const float* __restrict__ Wh,   const float* __restrict__ bh,
        const float* __restrict__ Wphi, const float* __restrict__ bphi,
        const float* __restrict__ z_pool, const float* __restrict__ znorm,
        float* __restrict__ partial, float* __restrict__ dsum,
        float* __restrict__ dsq) {
    const int b = blockIdx.x, tid = threadIdx.x;
    if (b < T_CNT) {
        __shared__ __align__(16) float mrow[H_DIM];
        __shared__ __align__(16) float hrow[H_DIM];
        __shared__ __align__(16) float cbuf[H_DIM];
        __shared__ float sred[H_DIM];
        __shared__ float sims[32];
        __shared__ float contrib[4];
        __shared__ float s_cn;

        // combine own 8 partial sums (fixed order) -> mean row
        const float* hp = hpart + (size_t)b * (H_CHUNKS * H_DIM);
        {
            float v = 0.f;
            #pragma unroll
            for (int c = 0; c < H_CHUNKS; ++c) v += hp[c * H_DIM + tid];
            mrow[tid] = v * (1.0f / (float)N_NODE);
        }
        __syncthreads();

        const int o = tid >> 1, half = tid & 1;
        {   // hrow = mrow @ Wh^T + bh
            const f4* w4 = (const f4*)(Wh + o * H_DIM + half * 64);
            const f4* x4 = (const f4*)(mrow + half * 64);
            float ps = 0.f;
            #pragma unroll
            for (int k = 0; k < 16; ++k) {
                f4 a = w4[k], x = x4[k];
                ps = fmaf(a.x, x.x, ps); ps = fmaf(a.y, x.y, ps);
                ps = fmaf(a.z, x.z, ps); ps = fmaf(a.w, x.w, ps);
            }
            ps += __shfl_xor(ps, 1);
            if (half == 0) hrow[o] = ps + bh[o];
        }
        __syncthreads();
        {   // cbuf = hrow @ Wphi^T + bphi ; squared norm
            const f4* w4 = (const f4*)(Wphi + o * H_DIM + half * 64);
            const f4* x4 = (const f4*)(hrow + half * 64);
            float ps = 0.f;
            #pragma unroll
            for (int k = 0; k < 16; ++k) {
                f4 a = w4[k], x = x4[k];
                ps = fmaf(a.x, x.x, ps); ps = fmaf(a.y, x.y, ps);
                ps = fmaf(a.z, x.z, ps); ps = fmaf(a.w, x.w, ps);
            }
            ps += __shfl_xor(ps, 1);
            if (half == 0) {
                float cv = ps + bphi[o];
                cbuf[o] = cv;
                sred[o] = cv * cv;
            }
        }
        __syncthreads();
        for (int st = 64; st >= 1; st >>= 1) {
            if (tid < st) sred[tid] += sred[tid + st];
            __syncthreads();
        }
        if (tid == 0) s_cn = fmaxf(sqrtf(sred[0]), EPS_F);
        __syncthreads();
        const float cn = s_cn;

        // 32 (i,m) pairs, 4 lanes per cosine dot
        const int pr = tid >> 2, l4 = tid & 3;
        const int i = pr >> 3, m = pr & 7;
        const int off = (m == 0) ? 0 : (NEG_DIST + m - 1);
        const int row = T_START + b + (i + 1) + off;
        const float* zr = z_pool + row * H_DIM;
        float num = 0.f;
        #pragma unroll 8
        for (int k = l4 * 32; k < l4 * 32 + 32; ++k)
            num = fmaf(zr[k], cbuf[k], num);
        num += __shfl_xor(num, 1);
        num += __shfl_xor(num, 2);
        if (l4 == 0) sims[pr] = num / (fmaxf(znorm[row], EPS_F) * cn);
        __syncthreads();
        if (tid < 4) {
            const float* sm = sims + tid * 8;
            float mx = sm[0];
            #pragma unroll
            for (int k = 1; k < M_SAMP; ++k) mx = fmaxf(mx, sm[k]);
            float se = 0.f;
            #pragma unroll
            for (int k = 0; k < M_SAMP; ++k) se += expf(sm[k] - mx);
            contrib[tid] = sm[0] - mx - logf(se);
        }
        __syncthreads();
        if (tid == 0)
            partial[b] = contrib[0] + contrib[1] + contrib[2] + contrib[3];
    } else {
        // ---- dist chunk: column sum/sumsq of 128 z_pool rows ----
        const int ch = b - T_CNT;
        const int s0 = ch * (S_DIM / DIST_B);
        float sum = 0.f, sq = 0.f;
        for (int s = s0; s < s0 + S_DIM / DIST_B; ++s) {
            float v = z_pool[s * H_DIM + tid];
            sum += v;
            sq = fmaf(v, v, sq);
        }
        dsum[ch * H_DIM + tid] = sum;
        dsq[ch * H_DIM + tid] = sq;
    }
}

// ---------------------------------------------------------------------------
// Kernel 3: final deterministic reductions -> both scalars.
// ---------------------------------------------------------------------------
__global__ __launch_bounds__(512) void final_kernel(
        const float* __restrict__ partial, const float* __restrict__ dsum,
        const float* __restrict__ dsq, float* __restrict__ out) {
    const int tid = threadIdx.x;
    __shared__ float red[512];
    __shared__ float dred[H_DIM];
    red[tid] = (tid < T_CNT) ? partial[tid] : 0.f;
    if (tid < H_DIM) {
        float S = 0.f, Q = 0.f;
        #pragma unroll
        for (int c = 0; c < DIST_B; ++c) {
            S += dsum[c * H_DIM + tid];
            Q += dsq[c * H_DIM + tid];
        }
        dred[tid] = Q - S * S / (float)S_DIM;
    }
    __syncthreads();
    for (int st = 256; st >= 1; st >>= 1) {
        if (tid < st) red[tid] += red[tid + st];
        __syncthreads();
    }
    for (int st = 64; st >= 1; st >>= 1) {
        if (tid < st) dred[tid] += dred[tid + st];
        __syncthreads();
    }
    if (tid == 0) {
        out[0] = red[0] / (-1.0f * (float)T_CNT * (float)TIMESPAN);
        out[1] = dred[0] / (float)S_DIM;
    }
}

extern "C" void kernel_launch(void* const* d_in, const int* in_sizes, int n_in,
                              void* d_out, int out_size, void* d_ws, size_t ws_size,
                              hipStream_t stream) {
    const float* all_h = (const float*)d_in[0];
    const float* all_z = (const float*)d_in[1];
    const float* Wh    = (const float*)d_in[2];
    const float* bh    = (const float*)d_in[3];
    const float* Wz    = (const float*)d_in[4];
    const float* bz    = (const float*)d_in[5];
    const float* Wphi  = (const float*)d_in[6];
    const float* bphi  = (const float*)d_in[7];
    float* out = (float*)d_out;

    float* ws = (float*)d_ws;
    float* z_pool  = ws;                               // 512*128
    float* znorm   = z_pool + S_DIM * H_DIM;           // 512
    float* hpart   = znorm + S_DIM;                    // 2824*128
    float* partial = hpart + T_CNT * H_CHUNKS * H_DIM; // 353
    float* dsum    = partial + T_CNT;                  // 4*128
    float* dsq     = dsum + DIST_B * H_DIM;            // 4*128

    pool_kernel<<<S_DIM + T_CNT * H_CHUNKS, 256, 0, stream>>>(
        all_h, all_z, Wz, bz, z_pool, znorm, hpart);
    nce_dist_kernel<<<T_CNT + DIST_B, 128, 0, stream>>>(
        hpart, Wh, bh, Wphi, bphi, z_pool, znorm, partial, dsum, dsq);
    final_kernel<<<1, 512, 0, stream>>>(partial, dsum, dsq, out);
}